// Round 2
// baseline (1749.736 us; speedup 1.0000x reference)
//
#include <hip/hip_runtime.h>
#include <hip/hip_bf16.h>

#define NPTS 4096
#define BATCH 4
#define BN (BATCH * NPTS)
#define DMODEL 128
#define DPTS 64
#define KNBR 16

typedef unsigned short u16;

__device__ __forceinline__ float bfu(u16 u) {
    union { unsigned int i; float f; } c; c.i = ((unsigned int)u) << 16; return c.f;
}
__device__ __forceinline__ u16 f2u(float x) {   // f32 -> bf16 bits, round-nearest-even
    unsigned int u = __float_as_uint(x);
    unsigned int r = u + 0x7FFFu + ((u >> 16) & 1u);
    return (u16)(r >> 16);
}
// MODE 0: inputs are bf16. MODE 1: inputs are f32.
template<int MODE> __device__ __forceinline__ float ld(const void* p, long i) {
    if (MODE == 0) return bfu(((const u16*)p)[i]);
    return ((const float*)p)[i];
}
template<int MODE> __device__ __forceinline__ void st_out(void* p, long i, float v) {
    if (MODE == 0) ((u16*)p)[i] = f2u(v);
    else ((float*)p)[i] = v;
}
// Stage a 128x128 weight matrix into LDS as bf16 bits.
template<int MODE> __device__ __forceinline__ void stageW(u16* sW, const void* W, int t, int nthr) {
    if (MODE == 0) {
        const uint4* src = (const uint4*)W; uint4* dst = (uint4*)sW;
        for (int i = t; i < (DMODEL * DMODEL) / 8; i += nthr) dst[i] = src[i];
    } else {
        const float* src = (const float*)W;
        for (int i = t; i < DMODEL * DMODEL; i += nthr) sW[i] = f2u(src[i]);
    }
}

// ---------------- dtype detector: bf16 data has no wild exponents; f32 read as u16 does.
__global__ void detect_kernel(const u16* w, int* flag) {
    int hits = 0;
    for (int i = threadIdx.x; i < 2048; i += 64) {
        unsigned e = (w[i] >> 7) & 0xFFu;
        if (e >= 132u || (e > 0u && e <= 90u)) hits++;   // |v|>=64 or 0<|v|<2^-37
    }
    for (int o = 32; o; o >>= 1) hits += __shfl_down(hits, o);
    if (threadIdx.x == 0) flag[0] = (hits > 64) ? 1 : 0;
}

// Insert (key,id) into ascending sorted top-16 register arrays. Caller ensures key < kd[15].
__device__ __forceinline__ void topk_insert(float key, int id, float (&kd)[16], int (&ki)[16]) {
    int pos = 0;
#pragma unroll
    for (int s = 0; s < 16; ++s) pos += (kd[s] <= key) ? 1 : 0;
#pragma unroll
    for (int s = 15; s > 0; --s) {
        if (s > pos) { kd[s] = kd[s - 1]; ki[s] = ki[s - 1]; }
    }
#pragma unroll
    for (int s = 0; s < 16; ++s) {
        if (s == pos) { kd[s] = key; ki[s] = id; }
    }
}

// ---------------- Kernel 1: f = feat@Wf1+bf1 ; q=f@Wq ; kf=f@Wk ; vf=f@Wv (per point)
template<int MODE>
__global__ __launch_bounds__(128) void qkv_kernel(
    const void* __restrict__ feat, const void* __restrict__ Wf1, const void* __restrict__ bf1,
    const void* __restrict__ Wq, const void* __restrict__ Wk, const void* __restrict__ Wv,
    u16* __restrict__ qw, u16* __restrict__ kfw, u16* __restrict__ vfw,
    const int* __restrict__ flag) {
    if (flag[0] != MODE) return;
    __shared__ float sFeat[DPTS];
    __shared__ float sF[DMODEL];
    const int p = blockIdx.x;
    const int j = threadIdx.x;
    if (j < DPTS) sFeat[j] = ld<MODE>(feat, (long)p * DPTS + j);
    __syncthreads();
    float acc = ld<MODE>(bf1, j);
#pragma unroll 4
    for (int i = 0; i < DPTS; ++i) acc += sFeat[i] * ld<MODE>(Wf1, (long)i * DMODEL + j);
    sF[j] = acc;
    __syncthreads();
    float aq = 0.f, ak = 0.f, av = 0.f;
#pragma unroll 4
    for (int i = 0; i < DMODEL; ++i) {
        float fi = sF[i];
        aq += fi * ld<MODE>(Wq, (long)i * DMODEL + j);
        ak += fi * ld<MODE>(Wk, (long)i * DMODEL + j);
        av += fi * ld<MODE>(Wv, (long)i * DMODEL + j);
    }
    long o = (long)p * DMODEL + j;
    qw[o] = f2u(aq); kfw[o] = f2u(ak); vfw[o] = f2u(av);
}

// ---------------- Kernel 2: KNN (16 smallest d2, self included) -----------------------
// Block: 256 threads = 64 points x 4 candidate-splits.
template<int MODE>
__global__ __launch_bounds__(256) void knn_kernel(
    const void* __restrict__ xyz, int* __restrict__ knnIdx, const int* __restrict__ flag) {
    if (flag[0] != MODE) return;
    __shared__ float4 sCand[256];
    __shared__ float sKeyM[64 * 65];
    __shared__ int   sIdxM[64 * 65];
    const int t = threadIdx.x;
    const int lp = t & 63;
    const int s = t >> 6;
    const int p = blockIdx.x * 64 + lp;       // all 64 points in same batch
    const int b = p >> 12;
    const int n = p & (NPTS - 1);
    const long xb = (long)b * NPTS * 3;
    const float px = ld<MODE>(xyz, xb + n * 3 + 0);
    const float py = ld<MODE>(xyz, xb + n * 3 + 1);
    const float pz = ld<MODE>(xyz, xb + n * 3 + 2);
    float kd[16]; int ki[16];
#pragma unroll
    for (int r = 0; r < 16; ++r) { kd[r] = 3e38f; ki[r] = 0; }

    for (int c = 0; c < NPTS / 256; ++c) {
        const int m0 = c * 256;
        {
            int m = m0 + t;
            float gx = ld<MODE>(xyz, xb + m * 3 + 0);
            float gy = ld<MODE>(xyz, xb + m * 3 + 1);
            float gz = ld<MODE>(xyz, xb + m * 3 + 2);
            sCand[t] = make_float4(gx, gy, gz, gx * gx + gy * gy + gz * gz);
        }
        __syncthreads();
        for (int u = 0; u < 64; ++u) {
            int cc = u * 4 + s;
            float4 cd = sCand[cc];
            float key = cd.w - 2.f * (px * cd.x + py * cd.y + pz * cd.z);  // d2 - ||p||^2
            if (key < kd[15]) topk_insert(key, m0 + cc, kd, ki);
        }
        __syncthreads();
    }
#pragma unroll
    for (int r = 0; r < 16; ++r) {
        sKeyM[lp * 65 + s * 16 + r] = kd[r];
        sIdxM[lp * 65 + s * 16 + r] = ki[r];
    }
    __syncthreads();
    if (t < 64) {
        float fd[16]; int fi[16];
#pragma unroll
        for (int r = 0; r < 16; ++r) { fd[r] = 3e38f; fi[r] = 0; }
        for (int e = 0; e < 64; ++e) {
            float key = sKeyM[t * 65 + e];
            int id = sIdxM[t * 65 + e];
            if (key < fd[15]) topk_insert(key, id, fd, fi);
        }
        int pp = blockIdx.x * 64 + t;
#pragma unroll
        for (int r = 0; r < 16; ++r) knnIdx[pp * 16 + r] = fi[r];
    }
}

// acc[k] = bias + sum_i sH[i][k] * W[i][j]  (sH reads are same-address broadcasts)
__device__ __forceinline__ void mlp_layer(const u16* sW, const float sH[][20], int j,
                                          float bias, float (&acc)[KNBR]) {
#pragma unroll
    for (int k = 0; k < KNBR; ++k) acc[k] = bias;
    for (int i = 0; i < DMODEL; ++i) {
        float w = bfu(sW[i * DMODEL + j]);
        const float* hr = sH[i];
#pragma unroll
        for (int k = 0; k < KNBR; ++k) acc[k] += hr[k] * w;
    }
}

// ---------------- Kernel 3: fused pos-enc MLP + gamma MLP + softmax + output ----------
// One block (128 threads) per point; thread j owns channel j for all 16 neighbors.
template<int MODE>
__global__ __launch_bounds__(128) void att_kernel(
    const void* __restrict__ xyz, const void* __restrict__ feat,
    const void* __restrict__ Wd1, const void* __restrict__ bd1,
    const void* __restrict__ Wd2, const void* __restrict__ bd2,
    const void* __restrict__ Wg1, const void* __restrict__ bg1,
    const void* __restrict__ Wg2, const void* __restrict__ bg2,
    const void* __restrict__ Wo, const void* __restrict__ bo,
    const u16* __restrict__ qw, const u16* __restrict__ kfw, const u16* __restrict__ vfw,
    const int* __restrict__ knnIdx, const int* __restrict__ flag,
    void* __restrict__ out) {
    if (flag[0] != MODE) return;
    __shared__ __align__(16) u16 sW[DMODEL * DMODEL];  // 32KB, streamed Wd2->Wg1->Wg2
    __shared__ float sH[DMODEL][20];                   // [channel i][neighbor k], padded
    __shared__ float sQ[DMODEL];
    __shared__ float sRes[DMODEL];
    __shared__ int   sIdx[KNBR];

    const int p = blockIdx.x;
    const int b = p >> 12;
    const int j = threadIdx.x;
    if (j < KNBR) sIdx[j] = knnIdx[p * KNBR + j];
    sQ[j] = bfu(qw[(long)p * DMODEL + j]);
    stageW<MODE>(sW, Wd2, j, 128);
    const float w0 = ld<MODE>(Wd1, j);
    const float w1 = ld<MODE>(Wd1, DMODEL + j);
    const float w2 = ld<MODE>(Wd1, 2 * DMODEL + j);
    const float bb1 = ld<MODE>(bd1, j);
    const float px = ld<MODE>(xyz, (long)p * 3 + 0);
    const float py = ld<MODE>(xyz, (long)p * 3 + 1);
    const float pz = ld<MODE>(xyz, (long)p * 3 + 2);
    __syncthreads();                                   // B0

    float kfv[KNBR], vfv[KNBR];
#pragma unroll
    for (int k = 0; k < KNBR; ++k) {
        long base = (long)b * NPTS + sIdx[k];
        kfv[k] = bfu(kfw[base * DMODEL + j]);
        vfv[k] = bfu(vfw[base * DMODEL + j]);
        float rx = px - ld<MODE>(xyz, base * 3 + 0);
        float ry = py - ld<MODE>(xyz, base * 3 + 1);
        float rz = pz - ld<MODE>(xyz, base * 3 + 2);
        sH[j][k] = fmaxf(bb1 + rx * w0 + ry * w1 + rz * w2, 0.f);   // h1
    }
    __syncthreads();                                   // B1

    float pe[KNBR];
    mlp_layer(sW, sH, j, ld<MODE>(bd2, j), pe);        // pe = h1@Wd2 + bd2
    __syncthreads();                                   // B2: sH & sW reads done
#pragma unroll
    for (int k = 0; k < KNBR; ++k) {
        vfv[k] += pe[k];                               // vpe (stays in regs)
        sH[j][k] = sQ[j] - kfv[k] + pe[k];             // a = q - k + pe
    }
    stageW<MODE>(sW, Wg1, j, 128);
    __syncthreads();                                   // B3

    float g[KNBR];
    mlp_layer(sW, sH, j, ld<MODE>(bg1, j), g);         // a@Wg1 + bg1
    __syncthreads();                                   // B4
#pragma unroll
    for (int k = 0; k < KNBR; ++k) sH[j][k] = fmaxf(g[k], 0.f);
    stageW<MODE>(sW, Wg2, j, 128);
    __syncthreads();                                   // B5

    float lgt[KNBR];
    mlp_layer(sW, sH, j, ld<MODE>(bg2, j), lgt);       // logits
    float mx = lgt[0];
#pragma unroll
    for (int k = 1; k < KNBR; ++k) mx = fmaxf(mx, lgt[k]);
    const float inv = 0.08838834764831845f;            // 1/sqrt(128)
    float ssum = 0.f, r = 0.f;
#pragma unroll
    for (int k = 0; k < KNBR; ++k) {
        float e = __expf((lgt[k] - mx) * inv);
        ssum += e;
        r += e * vfv[k];
    }
    sRes[j] = r / ssum;
    __syncthreads();                                   // B6

    if (j < DPTS) {
        float acc = ld<MODE>(bo, j);
#pragma unroll 4
        for (int i = 0; i < DMODEL; ++i) acc += sRes[i] * ld<MODE>(Wo, (long)i * DPTS + j);
        acc += ld<MODE>(feat, (long)p * DPTS + j);
        st_out<MODE>(out, (long)p * DPTS + j, acc);
    }
}

extern "C" void kernel_launch(void* const* d_in, const int* in_sizes, int n_in,
                              void* d_out, int out_size, void* d_ws, size_t ws_size,
                              hipStream_t stream) {
    (void)in_sizes; (void)n_in; (void)out_size; (void)ws_size;
    char* ws = (char*)d_ws;
    int* flag = (int*)ws;
    int* idx  = (int*)(ws + 256);
    u16* qw   = (u16*)(ws + 256 + (long)BN * KNBR * 4);  // after 1MB idx
    u16* kfw  = qw + (long)BN * DMODEL;
    u16* vfw  = kfw + (long)BN * DMODEL;                 // total ws ~13.25MB

    detect_kernel<<<1, 64, 0, stream>>>((const u16*)d_in[8], flag);

    qkv_kernel<0><<<BN, 128, 0, stream>>>(d_in[1], d_in[6], d_in[7], d_in[8], d_in[9],
                                          d_in[10], qw, kfw, vfw, flag);
    qkv_kernel<1><<<BN, 128, 0, stream>>>(d_in[1], d_in[6], d_in[7], d_in[8], d_in[9],
                                          d_in[10], qw, kfw, vfw, flag);
    knn_kernel<0><<<BN / 64, 256, 0, stream>>>(d_in[0], idx, flag);
    knn_kernel<1><<<BN / 64, 256, 0, stream>>>(d_in[0], idx, flag);
    att_kernel<0><<<BN, 128, 0, stream>>>(d_in[0], d_in[1], d_in[2], d_in[3], d_in[4],
                                          d_in[5], d_in[11], d_in[12], d_in[13], d_in[14],
                                          d_in[15], d_in[16], qw, kfw, vfw, idx, flag, d_out);
    att_kernel<1><<<BN, 128, 0, stream>>>(d_in[0], d_in[1], d_in[2], d_in[3], d_in[4],
                                          d_in[5], d_in[11], d_in[12], d_in[13], d_in[14],
                                          d_in[15], d_in[16], qw, kfw, vfw, idx, flag, d_out);
}

// Round 3
// 590.557 us; speedup vs baseline: 2.9629x; 2.9629x over previous
//
#include <hip/hip_runtime.h>
#include <hip/hip_bf16.h>

#define NPTS 4096
#define BATCH 4
#define BN (BATCH * NPTS)
#define DMODEL 128
#define DPTS 64
#define KNBR 16
#define SWS 136   // padded LDS row stride in bf16 elements (=68 dwords: quarter-wave
                  // b128 reads land on all 32 banks exactly 2x -> conflict-free)

typedef unsigned short u16;
typedef short bh8 __attribute__((ext_vector_type(8)));   // 8 bf16 (4 VGPRs) MFMA frag
typedef float f32x4 __attribute__((ext_vector_type(4))); // MFMA accumulator

__device__ __forceinline__ float bfu(u16 u) {
    union { unsigned int i; float f; } c; c.i = ((unsigned int)u) << 16; return c.f;
}
__device__ __forceinline__ u16 f2u(float x) {   // f32 -> bf16 bits, round-nearest-even
    unsigned int u = __float_as_uint(x);
    unsigned int r = u + 0x7FFFu + ((u >> 16) & 1u);
    return (u16)(r >> 16);
}
// MODE 0: inputs are bf16. MODE 1: inputs are f32.
template<int MODE> __device__ __forceinline__ float ld(const void* p, long i) {
    if (MODE == 0) return bfu(((const u16*)p)[i]);
    return ((const float*)p)[i];
}
template<int MODE> __device__ __forceinline__ void st_out(void* p, long i, float v) {
    if (MODE == 0) ((u16*)p)[i] = f2u(v);
    else ((float*)p)[i] = v;
}

// ---------------- dtype detector: bf16 data has no wild exponents; f32 read as u16 does.
__global__ void detect_kernel(const u16* w, int* flag) {
    int hits = 0;
    for (int i = threadIdx.x; i < 2048; i += 64) {
        unsigned e = (w[i] >> 7) & 0xFFu;
        if (e >= 132u || (e > 0u && e <= 90u)) hits++;
    }
    for (int o = 32; o; o >>= 1) hits += __shfl_down(hits, o);
    if (threadIdx.x == 0) flag[0] = (hits > 64) ? 1 : 0;
}

// ---------------- prep: transpose Wd2/Wg1/Wg2 -> [n][k] bf16; copy Wo -> bf16 -------
template<int MODE>
__global__ __launch_bounds__(256) void prep_kernel(
    const void* __restrict__ Wd2, const void* __restrict__ Wg1, const void* __restrict__ Wg2,
    const void* __restrict__ Wo,
    u16* __restrict__ WdT2, u16* __restrict__ WgT1, u16* __restrict__ WgT2,
    u16* __restrict__ WoC, const int* __restrict__ flag) {
    if (flag[0] != MODE) return;
    int idx = blockIdx.x * 256 + threadIdx.x;
    if (idx < 3 * 16384) {
        int m = idx >> 14, o = idx & 16383;
        int n = o >> 7, i = o & 127;
        const void* W = (m == 0) ? Wd2 : (m == 1) ? Wg1 : Wg2;
        u16* D = (m == 0) ? WdT2 : (m == 1) ? WgT1 : WgT2;
        D[o] = f2u(ld<MODE>(W, (long)i * 128 + n));   // W^T[n][i]
    } else {
        int o = idx - 3 * 16384;
        if (o < 8192) WoC[o] = f2u(ld<MODE>(Wo, o));
    }
}

// ---------------- Kernel 1: f = feat@Wf1+bf1 ; q=f@Wq ; kf=f@Wk ; vf=f@Wv (per point)
template<int MODE>
__global__ __launch_bounds__(128) void qkv_kernel(
    const void* __restrict__ feat, const void* __restrict__ Wf1, const void* __restrict__ bf1,
    const void* __restrict__ Wq, const void* __restrict__ Wk, const void* __restrict__ Wv,
    u16* __restrict__ qw, u16* __restrict__ kfw, u16* __restrict__ vfw,
    const int* __restrict__ flag) {
    if (flag[0] != MODE) return;
    __shared__ float sFeat[DPTS];
    __shared__ float sF[DMODEL];
    const int p = blockIdx.x;
    const int j = threadIdx.x;
    if (j < DPTS) sFeat[j] = ld<MODE>(feat, (long)p * DPTS + j);
    __syncthreads();
    float acc = ld<MODE>(bf1, j);
#pragma unroll 4
    for (int i = 0; i < DPTS; ++i) acc += sFeat[i] * ld<MODE>(Wf1, (long)i * DMODEL + j);
    sF[j] = acc;
    __syncthreads();
    float aq = 0.f, ak = 0.f, av = 0.f;
#pragma unroll 4
    for (int i = 0; i < DMODEL; ++i) {
        float fi = sF[i];
        aq += fi * ld<MODE>(Wq, (long)i * DMODEL + j);
        ak += fi * ld<MODE>(Wk, (long)i * DMODEL + j);
        av += fi * ld<MODE>(Wv, (long)i * DMODEL + j);
    }
    long o = (long)p * DMODEL + j;
    qw[o] = f2u(aq); kfw[o] = f2u(ak); vfw[o] = f2u(av);
}

// Branch-free sorted insert (ascending); caller guarantees key < kd[15].
__device__ __forceinline__ void topk_insert(float key, int id, float (&kd)[16], int (&ki)[16]) {
#pragma unroll
    for (int s = 15; s >= 1; --s) {
        bool stay  = kd[s] <= key;        // s < pos
        bool shift = kd[s - 1] > key;     // s > pos
        kd[s] = stay ? kd[s] : (shift ? kd[s - 1] : key);
        ki[s] = stay ? ki[s] : (shift ? ki[s - 1] : id);
    }
    if (kd[0] > key) { kd[0] = key; ki[0] = id; }
}

// ---------------- Kernel 2: KNN. Block = 32 points x 8 splits; grid 512. ------------
template<int MODE>
__global__ __launch_bounds__(256) void knn_kernel(
    const void* __restrict__ xyz, int* __restrict__ knnIdx, const int* __restrict__ flag) {
    if (flag[0] != MODE) return;
    __shared__ float4 sCand[256];
    __shared__ float sKeyM[32][129];
    __shared__ int   sIdxM[32][129];
    const int t = threadIdx.x;
    const int lp = t & 31;                  // point in block
    const int s = t >> 5;                   // split 0..7
    const int p = blockIdx.x * 32 + lp;     // 32 points, same batch
    const int b = p >> 12;
    const int n = p & (NPTS - 1);
    const long xb = (long)b * NPTS * 3;
    const float px = ld<MODE>(xyz, xb + n * 3 + 0);
    const float py = ld<MODE>(xyz, xb + n * 3 + 1);
    const float pz = ld<MODE>(xyz, xb + n * 3 + 2);
    float kd[16]; int ki[16];
#pragma unroll
    for (int r = 0; r < 16; ++r) { kd[r] = 3e38f; ki[r] = 0; }

    for (int c = 0; c < NPTS / 256; ++c) {
        const int m0 = c * 256;
        {
            int m = m0 + t;
            float gx = ld<MODE>(xyz, xb + m * 3 + 0);
            float gy = ld<MODE>(xyz, xb + m * 3 + 1);
            float gz = ld<MODE>(xyz, xb + m * 3 + 2);
            sCand[t] = make_float4(gx, gy, gz, gx * gx + gy * gy + gz * gz);
        }
        __syncthreads();
#pragma unroll 4
        for (int u = 0; u < 32; ++u) {
            int cc = u * 8 + s;
            float4 cd = sCand[cc];
            float key = cd.w - 2.f * (px * cd.x + py * cd.y + pz * cd.z);
            if (key < kd[15]) topk_insert(key, m0 + cc, kd, ki);
        }
        __syncthreads();
    }
#pragma unroll
    for (int r = 0; r < 16; ++r) {
        sKeyM[lp][s * 16 + r] = kd[r];
        sIdxM[lp][s * 16 + r] = ki[r];
    }
    __syncthreads();

    // tree-merge 8 sorted lists -> 1 (two-pointer merges via LDS, outputs in regs)
    float mk[16]; int mi[16];
#pragma unroll 1
    for (int lvl = 0; lvl < 2; ++lvl) {
        int nthr = 128 >> lvl;               // 128 then 64
        int pairs = 4 >> lvl;                // per point
        bool act = t < nthr;
        int pt = 0, a0 = 0, b0 = 0;
        if (act) {
            pt = t / pairs;
            int m = t % pairs;
            int span = 32 << lvl;
            a0 = m * span; b0 = a0 + (span >> 1);
            int pa = 0, pb = 0;
#pragma unroll
            for (int o = 0; o < 16; ++o) {
                float ka = sKeyM[pt][a0 + pa], kb = sKeyM[pt][b0 + pb];
                bool ta = ka <= kb;
                mk[o] = ta ? ka : kb;
                mi[o] = ta ? sIdxM[pt][a0 + pa] : sIdxM[pt][b0 + pb];
                pa += ta ? 1 : 0; pb += ta ? 0 : 1;
            }
        }
        __syncthreads();
        if (act) {
#pragma unroll
            for (int o = 0; o < 16; ++o) { sKeyM[pt][a0 + o] = mk[o]; sIdxM[pt][a0 + o] = mi[o]; }
        }
        __syncthreads();
    }
    if (t < 32) {   // final merge of lists at 0 and 64; write out
        int pa = 0, pb = 0;
        int pp = blockIdx.x * 32 + t;
#pragma unroll
        for (int o = 0; o < 16; ++o) {
            float ka = sKeyM[t][pa], kb = sKeyM[t][64 + pb];
            bool ta = ka <= kb;
            knnIdx[(long)pp * 16 + o] = ta ? sIdxM[t][pa] : sIdxM[t][64 + pb];
            pa += ta ? 1 : 0; pb += ta ? 0 : 1;
        }
    }
}

// ---- one MFMA GEMM phase: D[64x128] = sIn[64x128] @ W  (+bias, opt relu) -> sOut bf16
// 4 waves: wave w -> rows (w&1)*32..+32, cols (w>>1)*64..+64, as 2x4 tiles of 16x16.
__device__ __forceinline__ void mfma_phase(const u16* sIn, const u16* sWm,
                                           const float* bias, bool dorelu,
                                           u16* sOut, int t) {
    const int lane = t & 63, w = t >> 6;
    const int rg = (w & 1) * 32, cg = (w >> 1) * 64;
    const int lm = lane & 15, lq = lane >> 4;
    f32x4 acc[2][4];
#pragma unroll
    for (int rt = 0; rt < 2; ++rt)
#pragma unroll
        for (int ct = 0; ct < 4; ++ct) { acc[rt][ct][0]=0.f; acc[rt][ct][1]=0.f; acc[rt][ct][2]=0.f; acc[rt][ct][3]=0.f; }
#pragma unroll
    for (int kk = 0; kk < 4; ++kk) {
        const int ko = kk * 32 + lq * 8;
        bh8 a[2], bq[4];
        a[0] = *(const bh8*)(sIn + (rg + lm) * SWS + ko);
        a[1] = *(const bh8*)(sIn + (rg + 16 + lm) * SWS + ko);
#pragma unroll
        for (int ct = 0; ct < 4; ++ct)
            bq[ct] = *(const bh8*)(sWm + (cg + ct * 16 + lm) * SWS + ko);
#pragma unroll
        for (int rt = 0; rt < 2; ++rt)
#pragma unroll
            for (int ct = 0; ct < 4; ++ct)
                acc[rt][ct] = __builtin_amdgcn_mfma_f32_16x16x32_bf16(a[rt], bq[ct], acc[rt][ct], 0, 0, 0);
    }
    __syncthreads();   // all waves done reading sIn/sWm before overwrite (in==out safe)
#pragma unroll
    for (int rt = 0; rt < 2; ++rt)
#pragma unroll
        for (int ct = 0; ct < 4; ++ct) {
            const int col = cg + ct * 16 + lm;
            const float bj = bias[col];
#pragma unroll
            for (int r4 = 0; r4 < 4; ++r4) {
                int row = rg + rt * 16 + lq * 4 + r4;
                float v = acc[rt][ct][r4] + bj;
                if (dorelu) v = fmaxf(v, 0.f);
                sOut[row * SWS + col] = f2u(v);
            }
        }
}

// ---------------- Kernel 3: fused MFMA attention. Block = 4 points (64 rows). -------
template<int MODE>
__global__ __launch_bounds__(256, 2) void att_kernel(
    const void* __restrict__ xyz, const void* __restrict__ feat,
    const void* __restrict__ Wd1, const void* __restrict__ bd1, const void* __restrict__ bd2,
    const void* __restrict__ bg1, const void* __restrict__ bg2, const void* __restrict__ bo,
    const u16* __restrict__ WdT2, const u16* __restrict__ WgT1, const u16* __restrict__ WgT2,
    const u16* __restrict__ WoC,
    const u16* __restrict__ qw, const u16* __restrict__ kfw, const u16* __restrict__ vfw,
    const int* __restrict__ knnIdx, const int* __restrict__ flag,
    void* __restrict__ out) {
    if (flag[0] != MODE) return;
    __shared__ __align__(16) u16 sW[DMODEL * SWS];   // 34816 B, streamed WdT2->WgT1->WgT2(->Wo)
    __shared__ __align__(16) u16 sA[64 * SWS];       // 17408 B: H1 -> A -> G -> logits
    __shared__ __align__(16) u16 sPE[64 * SWS];      // 17408 B
    __shared__ float sRel[64][4];
    __shared__ float sRes[4][DMODEL];
    __shared__ float sBias[3 * DMODEL];              // bd2 | bg1 | bg2
    __shared__ int   sIdx[64];
    __shared__ u16   sQ[4 * DMODEL];

    const int p0 = blockIdx.x * 4;
    const long bbase = (long)(p0 >> 12) * NPTS;
    const int t = threadIdx.x;
    const int j = t & 127, rg2 = t >> 7;

    if (t < 64) sIdx[t] = knnIdx[(long)p0 * KNBR + t];
    __syncthreads();                                           // sIdx ready

    // ---- setup: rel vectors, q rows, biases, stage WdT2
    if (t < 64) {
        long nb = bbase + sIdx[t];
        int pl = t >> 4;
        sRel[t][0] = ld<MODE>(xyz, ((long)p0 + pl) * 3 + 0) - ld<MODE>(xyz, nb * 3 + 0);
        sRel[t][1] = ld<MODE>(xyz, ((long)p0 + pl) * 3 + 1) - ld<MODE>(xyz, nb * 3 + 1);
        sRel[t][2] = ld<MODE>(xyz, ((long)p0 + pl) * 3 + 2) - ld<MODE>(xyz, nb * 3 + 2);
    }
    if (t < 128) {
        sBias[t]       = ld<MODE>(bd2, t);
        sBias[128 + t] = ld<MODE>(bg1, t);
        sBias[256 + t] = ld<MODE>(bg2, t);
    }
    for (int i = t; i < 4 * DMODEL; i += 256) sQ[i] = qw[(long)p0 * DMODEL + i];
    for (int c = t; c < 2048; c += 256) {                      // WdT2 -> sW (padded rows)
        int row = c >> 4, c8 = c & 15;
        *(uint4*)(sW + row * SWS + c8 * 8) = ((const uint4*)WdT2)[c];
    }
    // H1 = relu(rel @ Wd1 + bd1) -> sA (each thread: 32 rows of its column j)
    {
        float w0 = ld<MODE>(Wd1, j), w1 = ld<MODE>(Wd1, DMODEL + j), w2 = ld<MODE>(Wd1, 2 * DMODEL + j);
        float b1 = ld<MODE>(bd1, j);
        __syncthreads();                                       // sRel ready
#pragma unroll 4
        for (int r = rg2 * 32; r < rg2 * 32 + 32; ++r) {
            float h = b1 + sRel[r][0] * w0 + sRel[r][1] * w1 + sRel[r][2] * w2;
            sA[r * SWS + j] = f2u(fmaxf(h, 0.f));
        }
    }
    __syncthreads();

    // ---- phase 1: PE = H1 @ Wd2 + bd2 -> sPE
    mfma_phase(sA, sW, sBias, false, sPE, t);
    __syncthreads();

    // ---- build A = q - kf + pe -> sA ; stage WgT1
#pragma unroll 4
    for (int r = rg2 * 32; r < rg2 * 32 + 32; ++r) {
        float qv = bfu(sQ[(r >> 4) * DMODEL + j]);
        float kv = bfu(kfw[(bbase + sIdx[r]) * (long)DMODEL + j]);
        sA[r * SWS + j] = f2u(qv - kv + bfu(sPE[r * SWS + j]));
    }
    for (int c = t; c < 2048; c += 256) {
        int row = c >> 4, c8 = c & 15;
        *(uint4*)(sW + row * SWS + c8 * 8) = ((const uint4*)WgT1)[c];
    }
    __syncthreads();

    // ---- phase 2: G = relu(A @ Wg1 + bg1) -> sA (in place)
    mfma_phase(sA, sW, sBias + 128, true, sA, t);
    __syncthreads();
    for (int c = t; c < 2048; c += 256) {
        int row = c >> 4, c8 = c & 15;
        *(uint4*)(sW + row * SWS + c8 * 8) = ((const uint4*)WgT2)[c];
    }
    __syncthreads();

    // ---- phase 3: logits = G @ Wg2 + bg2 -> sA (in place)
    mfma_phase(sA, sW, sBias + 256, false, sA, t);
    __syncthreads();

    // ---- stage Wo (flat [i][jo], 8192 u16) + softmax over k + weighted vpe sum
    for (int c = t; c < 1024; c += 256) ((uint4*)sW)[c] = ((const uint4*)WoC)[c];
    {
        const float inv = 0.08838834764831845f;   // 1/sqrt(128)
#pragma unroll
        for (int pp = 0; pp < 2; ++pp) {
            int pl = rg2 * 2 + pp;
            float lg[16];
            float mx = -3e38f;
#pragma unroll
            for (int k = 0; k < KNBR; ++k) {
                lg[k] = bfu(sA[(pl * 16 + k) * SWS + j]);
                mx = fmaxf(mx, lg[k]);
            }
            float ssum = 0.f, r = 0.f;
#pragma unroll
            for (int k = 0; k < KNBR; ++k) {
                float e = __expf((lg[k] - mx) * inv);
                float vpe = bfu(vfw[(bbase + sIdx[pl * 16 + k]) * (long)DMODEL + j])
                          + bfu(sPE[(pl * 16 + k) * SWS + j]);
                ssum += e;
                r += e * vpe;
            }
            sRes[pl][j] = r / ssum;
        }
    }
    __syncthreads();

    // ---- out = res @ Wo + bo + shortcut   (thread t: point t>>6, column t&63)
    {
        int jo = t & 63, pl = t >> 6;
        float acc = ld<MODE>(bo, jo);
#pragma unroll 4
        for (int i = 0; i < DMODEL; ++i) acc += sRes[pl][i] * bfu(sW[i * DPTS + jo]);
        acc += ld<MODE>(feat, ((long)p0 + pl) * DPTS + jo);
        st_out<MODE>(out, ((long)p0 + pl) * DPTS + jo, acc);
    }
}

extern "C" void kernel_launch(void* const* d_in, const int* in_sizes, int n_in,
                              void* d_out, int out_size, void* d_ws, size_t ws_size,
                              hipStream_t stream) {
    (void)in_sizes; (void)n_in; (void)out_size; (void)ws_size;
    char* ws = (char*)d_ws;
    int* flag = (int*)ws;
    int* idx  = (int*)(ws + 256);
    u16* qw   = (u16*)(ws + 256 + (long)BN * KNBR * 4);
    u16* kfw  = qw + (long)BN * DMODEL;
    u16* vfw  = kfw + (long)BN * DMODEL;
    u16* WdT2 = vfw + (long)BN * DMODEL;
    u16* WgT1 = WdT2 + 16384;
    u16* WgT2 = WgT1 + 16384;
    u16* WoC  = WgT2 + 16384;                 // total ws ~13.4 MB

    detect_kernel<<<1, 64, 0, stream>>>((const u16*)d_in[8], flag);

    prep_kernel<0><<<224, 256, 0, stream>>>(d_in[4], d_in[11], d_in[13], d_in[15],
                                            WdT2, WgT1, WgT2, WoC, flag);
    prep_kernel<1><<<224, 256, 0, stream>>>(d_in[4], d_in[11], d_in[13], d_in[15],
                                            WdT2, WgT1, WgT2, WoC, flag);
    qkv_kernel<0><<<BN, 128, 0, stream>>>(d_in[1], d_in[6], d_in[7], d_in[8], d_in[9],
                                          d_in[10], qw, kfw, vfw, flag);
    qkv_kernel<1><<<BN, 128, 0, stream>>>(d_in[1], d_in[6], d_in[7], d_in[8], d_in[9],
                                          d_in[10], qw, kfw, vfw, flag);
    knn_kernel<0><<<BN / 32, 256, 0, stream>>>(d_in[0], idx, flag);
    knn_kernel<1><<<BN / 32, 256, 0, stream>>>(d_in[0], idx, flag);
    att_kernel<0><<<BN / 4, 256, 0, stream>>>(d_in[0], d_in[1], d_in[2], d_in[3], d_in[5],
                                              d_in[12], d_in[14], d_in[16],
                                              WdT2, WgT1, WgT2, WoC,
                                              qw, kfw, vfw, idx, flag, d_out);
    att_kernel<1><<<BN / 4, 256, 0, stream>>>(d_in[0], d_in[1], d_in[2], d_in[3], d_in[5],
                                              d_in[12], d_in[14], d_in[16],
                                              WdT2, WgT1, WgT2, WoC,
                                              qw, kfw, vfw, idx, flag, d_out);
}

// Round 4
// 393.156 us; speedup vs baseline: 4.4505x; 1.5021x over previous
//
#include <hip/hip_runtime.h>
#include <hip/hip_bf16.h>

#define NPTS 4096
#define BATCH 4
#define BN (BATCH * NPTS)
#define DMODEL 128
#define DPTS 64
#define KNBR 16
#define SWS 136   // padded LDS row stride in bf16 elements (=68 dwords: quarter-wave
                  // b128 reads land on all 32 banks exactly 2x -> conflict-free)

typedef unsigned short u16;
typedef short bh8 __attribute__((ext_vector_type(8)));   // 8 bf16 (4 VGPRs) MFMA frag
typedef float f32x4 __attribute__((ext_vector_type(4))); // MFMA accumulator

__device__ __forceinline__ float bfu(u16 u) {
    union { unsigned int i; float f; } c; c.i = ((unsigned int)u) << 16; return c.f;
}
__device__ __forceinline__ u16 f2u(float x) {   // f32 -> bf16 bits, round-nearest-even
    unsigned int u = __float_as_uint(x);
    unsigned int r = u + 0x7FFFu + ((u >> 16) & 1u);
    return (u16)(r >> 16);
}
// MODE 0: inputs are bf16. MODE 1: inputs are f32.
template<int MODE> __device__ __forceinline__ float ld(const void* p, long i) {
    if (MODE == 0) return bfu(((const u16*)p)[i]);
    return ((const float*)p)[i];
}
template<int MODE> __device__ __forceinline__ void st_out(void* p, long i, float v) {
    if (MODE == 0) ((u16*)p)[i] = f2u(v);
    else ((float*)p)[i] = v;
}

// ---------------- dtype detector: bf16 data has no wild exponents; f32 read as u16 does.
__global__ void detect_kernel(const u16* w, int* flag) {
    int hits = 0;
    for (int i = threadIdx.x; i < 2048; i += 64) {
        unsigned e = (w[i] >> 7) & 0xFFu;
        if (e >= 132u || (e > 0u && e <= 90u)) hits++;
    }
    for (int o = 32; o; o >>= 1) hits += __shfl_down(hits, o);
    if (threadIdx.x == 0) flag[0] = (hits > 64) ? 1 : 0;
}

// ---------------- prep: transpose Wd2/Wg1/Wg2/Wq/Wk/Wv -> [n][k]; Wf1 -> [n][k]; Wo copy
template<int MODE>
__global__ __launch_bounds__(256) void prep_kernel(
    const void* __restrict__ Wd2, const void* __restrict__ Wg1, const void* __restrict__ Wg2,
    const void* __restrict__ Wo, const void* __restrict__ Wq, const void* __restrict__ Wk,
    const void* __restrict__ Wv, const void* __restrict__ Wf1,
    u16* __restrict__ WdT2, u16* __restrict__ WgT1, u16* __restrict__ WgT2,
    u16* __restrict__ WoC, u16* __restrict__ WqT, u16* __restrict__ WkT,
    u16* __restrict__ WvT, u16* __restrict__ WfT, const int* __restrict__ flag) {
    if (flag[0] != MODE) return;
    int idx = blockIdx.x * 256 + threadIdx.x;
    if (idx < 6 * 16384) {
        int m = idx >> 14, o = idx & 16383;
        int n = o >> 7, i = o & 127;
        const void* W = (m == 0) ? Wd2 : (m == 1) ? Wg1 : (m == 2) ? Wg2
                      : (m == 3) ? Wq  : (m == 4) ? Wk  : Wv;
        u16* D = (m == 0) ? WdT2 : (m == 1) ? WgT1 : (m == 2) ? WgT2
               : (m == 3) ? WqT  : (m == 4) ? WkT  : WvT;
        D[o] = f2u(ld<MODE>(W, (long)i * 128 + n));   // W^T[n][i]
    } else {
        int o = idx - 6 * 16384;
        if (o < 8192) {
            int n = o >> 6, k2 = o & 63;
            WfT[o] = f2u(ld<MODE>(Wf1, (long)k2 * 128 + n));   // Wf1^T[n][k]
        } else {
            int o2 = o - 8192;
            if (o2 < 8192) WoC[o2] = f2u(ld<MODE>(Wo, o2));
        }
    }
}

// ---------------- Kernel 1 (MFMA): f = feat@Wf1+bf1 ; q=f@Wq ; kf=f@Wk ; vf=f@Wv ----
// Block = 64 points (rows), 4 waves. Wave w: rows (w&1)*32..+32, cols (w>>1)*64..+64.
template<int MODE>
__global__ __launch_bounds__(256) void qkv_kernel(
    const void* __restrict__ feat, const void* __restrict__ bf1v,
    const u16* __restrict__ WfT, const u16* __restrict__ WqT,
    const u16* __restrict__ WkT, const u16* __restrict__ WvT,
    u16* __restrict__ qw, u16* __restrict__ kfw, u16* __restrict__ vfw,
    const int* __restrict__ flag) {
    if (flag[0] != MODE) return;
    __shared__ __align__(16) u16 sFeat[64 * 72];     // feat tile, pad 72 (144B rows, 16B-mult)
    __shared__ __align__(16) u16 sW[DMODEL * SWS];   // streamed WfT->WqT->WkT->WvT
    __shared__ __align__(16) u16 sF[64 * SWS];       // f tile (bf16)
    const int t = threadIdx.x;
    const int p0 = blockIdx.x * 64;
    const int lane = t & 63, w = t >> 6;
    const int rg = (w & 1) * 32, cg = (w >> 1) * 64;
    const int lm = lane & 15, lq = lane >> 4;

    // stage feat tile [64 x 64]
    for (int i = t; i < 512; i += 256) {
        int r = i >> 3, c8 = i & 7;
        u16 tmp[8];
        if (MODE == 0) {
            *(uint4*)tmp = *((const uint4*)feat + (long)(p0 + r) * 8 + c8);
        } else {
            const float* fp = (const float*)feat + (long)(p0 + r) * 64 + c8 * 8;
#pragma unroll
            for (int u = 0; u < 8; ++u) tmp[u] = f2u(fp[u]);
        }
        *(uint4*)(sFeat + r * 72 + c8 * 8) = *(uint4*)tmp;
    }
    // stage WfT [128 x 64]
    for (int i = t; i < 1024; i += 256) {
        int r = i >> 3, c8 = i & 7;
        *(uint4*)(sW + r * SWS + c8 * 8) = ((const uint4*)WfT)[i];
    }
    __syncthreads();

    // GEMM1: f = feat @ Wf1 + bf1 -> sF
    {
        f32x4 acc[2][4];
#pragma unroll
        for (int rt = 0; rt < 2; ++rt)
#pragma unroll
            for (int ct = 0; ct < 4; ++ct) { acc[rt][ct][0]=0.f; acc[rt][ct][1]=0.f; acc[rt][ct][2]=0.f; acc[rt][ct][3]=0.f; }
#pragma unroll
        for (int kk = 0; kk < 2; ++kk) {
            const int ko = kk * 32 + lq * 8;
            bh8 a0 = *(const bh8*)(sFeat + (rg + lm) * 72 + ko);
            bh8 a1 = *(const bh8*)(sFeat + (rg + 16 + lm) * 72 + ko);
            bh8 bq[4];
#pragma unroll
            for (int ct = 0; ct < 4; ++ct)
                bq[ct] = *(const bh8*)(sW + (cg + ct * 16 + lm) * SWS + ko);
#pragma unroll
            for (int ct = 0; ct < 4; ++ct) {
                acc[0][ct] = __builtin_amdgcn_mfma_f32_16x16x32_bf16(a0, bq[ct], acc[0][ct], 0, 0, 0);
                acc[1][ct] = __builtin_amdgcn_mfma_f32_16x16x32_bf16(a1, bq[ct], acc[1][ct], 0, 0, 0);
            }
        }
        __syncthreads();   // all reads of sW(WfT)/sFeat done
#pragma unroll
        for (int rt = 0; rt < 2; ++rt)
#pragma unroll
            for (int ct = 0; ct < 4; ++ct) {
                const int col = cg + ct * 16 + lm;
                const float bj = ld<MODE>(bf1v, col);
#pragma unroll
                for (int r4 = 0; r4 < 4; ++r4) {
                    int row = rg + rt * 16 + lq * 4 + r4;
                    sF[row * SWS + col] = f2u(acc[rt][ct][r4] + bj);
                }
            }
    }
    __syncthreads();

    // GEMM2-4: q/k/v = f @ W  (W streamed through sW)
    const u16* Ws[3] = {WqT, WkT, WvT};
    u16* Os[3] = {qw, kfw, vfw};
#pragma unroll 1
    for (int m = 0; m < 3; ++m) {
        for (int i = t; i < 2048; i += 256) {
            int r = i >> 4, c8 = i & 15;
            *(uint4*)(sW + r * SWS + c8 * 8) = ((const uint4*)Ws[m])[i];
        }
        __syncthreads();
        f32x4 acc[2][4];
#pragma unroll
        for (int rt = 0; rt < 2; ++rt)
#pragma unroll
            for (int ct = 0; ct < 4; ++ct) { acc[rt][ct][0]=0.f; acc[rt][ct][1]=0.f; acc[rt][ct][2]=0.f; acc[rt][ct][3]=0.f; }
#pragma unroll
        for (int kk = 0; kk < 4; ++kk) {
            const int ko = kk * 32 + lq * 8;
            bh8 a0 = *(const bh8*)(sF + (rg + lm) * SWS + ko);
            bh8 a1 = *(const bh8*)(sF + (rg + 16 + lm) * SWS + ko);
            bh8 bq[4];
#pragma unroll
            for (int ct = 0; ct < 4; ++ct)
                bq[ct] = *(const bh8*)(sW + (cg + ct * 16 + lm) * SWS + ko);
#pragma unroll
            for (int ct = 0; ct < 4; ++ct) {
                acc[0][ct] = __builtin_amdgcn_mfma_f32_16x16x32_bf16(a0, bq[ct], acc[0][ct], 0, 0, 0);
                acc[1][ct] = __builtin_amdgcn_mfma_f32_16x16x32_bf16(a1, bq[ct], acc[1][ct], 0, 0, 0);
            }
        }
#pragma unroll
        for (int rt = 0; rt < 2; ++rt)
#pragma unroll
            for (int ct = 0; ct < 4; ++ct) {
                const int col = cg + ct * 16 + lm;
#pragma unroll
                for (int r4 = 0; r4 < 4; ++r4) {
                    int row = rg + rt * 16 + lq * 4 + r4;
                    Os[m][(long)(p0 + row) * DMODEL + col] = f2u(acc[rt][ct][r4]);
                }
            }
        __syncthreads();   // sW reads done before next restage
    }
}

// ---------------- Kernel 2: KNN, wave-cooperative top-16. One wave per point. -------
// Lanes hold the sorted list (one element/lane, ascending; lanes 0..15 are the answer).
// Eval 64 candidates/iter vs uniform threshold T; ballot; serial wave-uniform inserts.
template<int MODE>
__global__ __launch_bounds__(256) void knn_kernel(
    const void* __restrict__ xyz, int* __restrict__ knnIdx, const int* __restrict__ flag) {
    if (flag[0] != MODE) return;
    __shared__ __align__(8) u16 sXyz[NPTS * 4];   // 32KB: (x,y,z,0) bf16
    __shared__ float sN2[NPTS];                   // 16KB: |c|^2
    const int t = threadIdx.x;
    const int p0 = blockIdx.x * 4;                // 4 points (same batch), 1 per wave
    const long xb = (long)(p0 >> 12) * NPTS * 3;
    for (int m = t; m < NPTS; m += 256) {
        float gx = ld<MODE>(xyz, xb + m * 3 + 0);
        float gy = ld<MODE>(xyz, xb + m * 3 + 1);
        float gz = ld<MODE>(xyz, xb + m * 3 + 2);
        uint2 pk;
        pk.x = (unsigned)f2u(gx) | ((unsigned)f2u(gy) << 16);
        pk.y = (unsigned)f2u(gz);
        *(uint2*)(sXyz + m * 4) = pk;
        sN2[m] = gx * gx + gy * gy + gz * gz;
    }
    __syncthreads();
    const int w = t >> 6, lane = t & 63;
    const int pl = (p0 & (NPTS - 1)) + w;
    uint2 qv = *(const uint2*)(sXyz + pl * 4);
    const float px = __uint_as_float(qv.x << 16);
    const float py = __uint_as_float(qv.x & 0xFFFF0000u);
    const float pz = __uint_as_float(qv.y << 16);
    float kd = 3e38f; int ki = 0;
    float T = 3e38f;
#pragma unroll 1
    for (int it = 0; it < NPTS / 64; ++it) {
        const int c = it * 64 + lane;
        uint2 cd = *(const uint2*)(sXyz + c * 4);
        float cx = __uint_as_float(cd.x << 16);
        float cy = __uint_as_float(cd.x & 0xFFFF0000u);
        float cz = __uint_as_float(cd.y << 16);
        float key = sN2[c] - 2.f * (px * cx + py * cy + pz * cz);  // d2 - |p|^2
        unsigned long long mask = __ballot(key < T);
        while (mask) {
            int l = __ffsll(mask) - 1;
            mask &= mask - 1;
            float kk = __uint_as_float(__builtin_amdgcn_readlane(__float_as_uint(key), l));
            if (kk < T) {                     // T may have tightened; uniform branch
                int ii = it * 64 + l;         // uniform
                float pkd = __shfl_up(kd, 1);
                int   pki = __shfl_up(ki, 1);
                if (lane == 0) pkd = -3e38f;
                bool pg = pkd > kk, cg = kd > kk;
                kd = pg ? pkd : (cg ? kk : kd);
                ki = pg ? pki : (cg ? ii : ki);
                T = __uint_as_float(__builtin_amdgcn_readlane(__float_as_uint(kd), 15));
            }
        }
    }
    if (lane < 16) knnIdx[(long)(p0 + w) * 16 + lane] = ki;
}

// ---- one MFMA GEMM phase: D[64x128] = sIn[64x128] @ W  (+bias, opt relu) -> sOut bf16
__device__ __forceinline__ void mfma_phase(const u16* sIn, const u16* sWm,
                                           const float* bias, bool dorelu,
                                           u16* sOut, int t) {
    const int lane = t & 63, w = t >> 6;
    const int rg = (w & 1) * 32, cg = (w >> 1) * 64;
    const int lm = lane & 15, lq = lane >> 4;
    f32x4 acc[2][4];
#pragma unroll
    for (int rt = 0; rt < 2; ++rt)
#pragma unroll
        for (int ct = 0; ct < 4; ++ct) { acc[rt][ct][0]=0.f; acc[rt][ct][1]=0.f; acc[rt][ct][2]=0.f; acc[rt][ct][3]=0.f; }
#pragma unroll
    for (int kk = 0; kk < 4; ++kk) {
        const int ko = kk * 32 + lq * 8;
        bh8 a[2], bq[4];
        a[0] = *(const bh8*)(sIn + (rg + lm) * SWS + ko);
        a[1] = *(const bh8*)(sIn + (rg + 16 + lm) * SWS + ko);
#pragma unroll
        for (int ct = 0; ct < 4; ++ct)
            bq[ct] = *(const bh8*)(sWm + (cg + ct * 16 + lm) * SWS + ko);
#pragma unroll
        for (int rt = 0; rt < 2; ++rt)
#pragma unroll
            for (int ct = 0; ct < 4; ++ct)
                acc[rt][ct] = __builtin_amdgcn_mfma_f32_16x16x32_bf16(a[rt], bq[ct], acc[rt][ct], 0, 0, 0);
    }
    __syncthreads();   // all waves done reading sIn/sWm before overwrite (in==out safe)
#pragma unroll
    for (int rt = 0; rt < 2; ++rt)
#pragma unroll
        for (int ct = 0; ct < 4; ++ct) {
            const int col = cg + ct * 16 + lm;
            const float bj = bias[col];
#pragma unroll
            for (int r4 = 0; r4 < 4; ++r4) {
                int row = rg + rt * 16 + lq * 4 + r4;
                float v = acc[rt][ct][r4] + bj;
                if (dorelu) v = fmaxf(v, 0.f);
                sOut[row * SWS + col] = f2u(v);
            }
        }
}

// ---------------- Kernel 3: fused MFMA attention. Block = 4 points (64 rows). -------
template<int MODE>
__global__ __launch_bounds__(256, 2) void att_kernel(
    const void* __restrict__ xyz, const void* __restrict__ feat,
    const void* __restrict__ Wd1, const void* __restrict__ bd1, const void* __restrict__ bd2,
    const void* __restrict__ bg1, const void* __restrict__ bg2, const void* __restrict__ bo,
    const u16* __restrict__ WdT2, const u16* __restrict__ WgT1, const u16* __restrict__ WgT2,
    const u16* __restrict__ WoC,
    const u16* __restrict__ qw, const u16* __restrict__ kfw, const u16* __restrict__ vfw,
    const int* __restrict__ knnIdx, const int* __restrict__ flag,
    void* __restrict__ out) {
    if (flag[0] != MODE) return;
    __shared__ __align__(16) u16 sW[DMODEL * SWS];   // streamed WdT2->WgT1->WgT2(->Wo)
    __shared__ __align__(16) u16 sA[64 * SWS];       // H1 -> A -> G -> logits
    __shared__ __align__(16) u16 sPE[64 * SWS];
    __shared__ float sRel[64][4];
    __shared__ float sRes[4][DMODEL];
    __shared__ float sBias[3 * DMODEL];              // bd2 | bg1 | bg2
    __shared__ int   sIdx[64];
    __shared__ u16   sQ[4 * DMODEL];

    const int p0 = blockIdx.x * 4;
    const long bbase = (long)(p0 >> 12) * NPTS;
    const int t = threadIdx.x;
    const int j = t & 127, rg2 = t >> 7;

    if (t < 64) sIdx[t] = knnIdx[(long)p0 * KNBR + t];
    __syncthreads();                                           // sIdx ready

    if (t < 64) {
        long nb = bbase + sIdx[t];
        int pl = t >> 4;
        sRel[t][0] = ld<MODE>(xyz, ((long)p0 + pl) * 3 + 0) - ld<MODE>(xyz, nb * 3 + 0);
        sRel[t][1] = ld<MODE>(xyz, ((long)p0 + pl) * 3 + 1) - ld<MODE>(xyz, nb * 3 + 1);
        sRel[t][2] = ld<MODE>(xyz, ((long)p0 + pl) * 3 + 2) - ld<MODE>(xyz, nb * 3 + 2);
    }
    if (t < 128) {
        sBias[t]       = ld<MODE>(bd2, t);
        sBias[128 + t] = ld<MODE>(bg1, t);
        sBias[256 + t] = ld<MODE>(bg2, t);
    }
    for (int i = t; i < 4 * DMODEL; i += 256) sQ[i] = qw[(long)p0 * DMODEL + i];
    for (int c = t; c < 2048; c += 256) {                      // WdT2 -> sW
        int row = c >> 4, c8 = c & 15;
        *(uint4*)(sW + row * SWS + c8 * 8) = ((const uint4*)WdT2)[c];
    }
    {
        float w0 = ld<MODE>(Wd1, j), w1 = ld<MODE>(Wd1, DMODEL + j), w2 = ld<MODE>(Wd1, 2 * DMODEL + j);
        float b1 = ld<MODE>(bd1, j);
        __syncthreads();                                       // sRel ready
#pragma unroll 4
        for (int r = rg2 * 32; r < rg2 * 32 + 32; ++r) {
            float h = b1 + sRel[r][0] * w0 + sRel[r][1] * w1 + sRel[r][2] * w2;
            sA[r * SWS + j] = f2u(fmaxf(h, 0.f));
        }
    }
    __syncthreads();

    mfma_phase(sA, sW, sBias, false, sPE, t);                  // PE = H1@Wd2+bd2
    __syncthreads();

#pragma unroll 4
    for (int r = rg2 * 32; r < rg2 * 32 + 32; ++r) {
        float qv2 = bfu(sQ[(r >> 4) * DMODEL + j]);
        float kv = bfu(kfw[(bbase + sIdx[r]) * (long)DMODEL + j]);
        sA[r * SWS + j] = f2u(qv2 - kv + bfu(sPE[r * SWS + j]));
    }
    for (int c = t; c < 2048; c += 256) {
        int row = c >> 4, c8 = c & 15;
        *(uint4*)(sW + row * SWS + c8 * 8) = ((const uint4*)WgT1)[c];
    }
    __syncthreads();

    mfma_phase(sA, sW, sBias + 128, true, sA, t);              // G = relu(A@Wg1+bg1)
    __syncthreads();
    for (int c = t; c < 2048; c += 256) {
        int row = c >> 4, c8 = c & 15;
        *(uint4*)(sW + row * SWS + c8 * 8) = ((const uint4*)WgT2)[c];
    }
    __syncthreads();

    mfma_phase(sA, sW, sBias + 256, false, sA, t);             // logits = G@Wg2+bg2
    __syncthreads();

    for (int c = t; c < 1024; c += 256) ((uint4*)sW)[c] = ((const uint4*)WoC)[c];
    {
        const float inv = 0.08838834764831845f;   // 1/sqrt(128)
#pragma unroll
        for (int pp = 0; pp < 2; ++pp) {
            int pl = rg2 * 2 + pp;
            float lg[16];
            float mx = -3e38f;
#pragma unroll
            for (int k = 0; k < KNBR; ++k) {
                lg[k] = bfu(sA[(pl * 16 + k) * SWS + j]);
                mx = fmaxf(mx, lg[k]);
            }
            float ssum = 0.f, r = 0.f;
#pragma unroll
            for (int k = 0; k < KNBR; ++k) {
                float e = __expf((lg[k] - mx) * inv);
                float vpe = bfu(vfw[(bbase + sIdx[pl * 16 + k]) * (long)DMODEL + j])
                          + bfu(sPE[(pl * 16 + k) * SWS + j]);
                ssum += e;
                r += e * vpe;
            }
            sRes[pl][j] = r / ssum;
        }
    }
    __syncthreads();

    {
        int jo = t & 63, pl = t >> 6;
        float acc = ld<MODE>(bo, jo);
#pragma unroll 4
        for (int i = 0; i < DMODEL; ++i) acc += sRes[pl][i] * bfu(sW[i * DPTS + jo]);
        acc += ld<MODE>(feat, ((long)p0 + pl) * DPTS + jo);
        st_out<MODE>(out, ((long)p0 + pl) * DPTS + jo, acc);
    }
}

extern "C" void kernel_launch(void* const* d_in, const int* in_sizes, int n_in,
                              void* d_out, int out_size, void* d_ws, size_t ws_size,
                              hipStream_t stream) {
    (void)in_sizes; (void)n_in; (void)out_size; (void)ws_size;
    char* ws = (char*)d_ws;
    int* flag = (int*)ws;
    int* idx  = (int*)(ws + 256);
    u16* qw   = (u16*)(ws + 256 + (long)BN * KNBR * 4);
    u16* kfw  = qw + (long)BN * DMODEL;
    u16* vfw  = kfw + (long)BN * DMODEL;
    u16* WdT2 = vfw + (long)BN * DMODEL;
    u16* WgT1 = WdT2 + 16384;
    u16* WgT2 = WgT1 + 16384;
    u16* WoC  = WgT2 + 16384;
    u16* WqT  = WoC + 8192;
    u16* WkT  = WqT + 16384;
    u16* WvT  = WkT + 16384;
    u16* WfT  = WvT + 16384;                  // total ws ~13.6 MB

    detect_kernel<<<1, 64, 0, stream>>>((const u16*)d_in[8], flag);

    prep_kernel<0><<<448, 256, 0, stream>>>(d_in[4], d_in[11], d_in[13], d_in[15],
                                            d_in[8], d_in[9], d_in[10], d_in[6],
                                            WdT2, WgT1, WgT2, WoC, WqT, WkT, WvT, WfT, flag);
    prep_kernel<1><<<448, 256, 0, stream>>>(d_in[4], d_in[11], d_in[13], d_in[15],
                                            d_in[8], d_in[9], d_in[10], d_in[6],
                                            WdT2, WgT1, WgT2, WoC, WqT, WkT, WvT, WfT, flag);
    qkv_kernel<0><<<BN / 64, 256, 0, stream>>>(d_in[1], d_in[7], WfT, WqT, WkT, WvT,
                                               qw, kfw, vfw, flag);
    qkv_kernel<1><<<BN / 64, 256, 0, stream>>>(d_in[1], d_in[7], WfT, WqT, WkT, WvT,
                                               qw, kfw, vfw, flag);
    knn_kernel<0><<<BN / 4, 256, 0, stream>>>(d_in[0], idx, flag);
    knn_kernel<1><<<BN / 4, 256, 0, stream>>>(d_in[0], idx, flag);
    att_kernel<0><<<BN / 4, 256, 0, stream>>>(d_in[0], d_in[1], d_in[2], d_in[3], d_in[5],
                                              d_in[12], d_in[14], d_in[16],
                                              WdT2, WgT1, WgT2, WoC,
                                              qw, kfw, vfw, idx, flag, d_out);
    att_kernel<1><<<BN / 4, 256, 0, stream>>>(d_in[0], d_in[1], d_in[2], d_in[3], d_in[5],
                                              d_in[12], d_in[14], d_in[16],
                                              WdT2, WgT1, WgT2, WoC,
                                              qw, kfw, vfw, idx, flag, d_out);
}

// Round 5
// 391.662 us; speedup vs baseline: 4.4675x; 1.0038x over previous
//
#include <hip/hip_runtime.h>
#include <hip/hip_bf16.h>

#define NPTS 4096
#define BATCH 4
#define BN (BATCH * NPTS)
#define DMODEL 128
#define DPTS 64
#define KNBR 16
#define SWS 136   // padded LDS row stride in bf16 elements (68 dwords ≡ 4 mod 32 banks)

typedef unsigned short u16;
typedef unsigned int u32;
typedef short bh8 __attribute__((ext_vector_type(8)));   // 8 bf16 (4 VGPRs) MFMA frag
typedef float f32x4 __attribute__((ext_vector_type(4))); // MFMA accumulator

__device__ __forceinline__ float bfu(u16 u) {
    union { u32 i; float f; } c; c.i = ((u32)u) << 16; return c.f;
}
__device__ __forceinline__ u16 f2u(float x) {   // f32 -> bf16 bits, round-nearest-even
    u32 u = __float_as_uint(x);
    u32 r = u + 0x7FFFu + ((u >> 16) & 1u);
    return (u16)(r >> 16);
}
__device__ __forceinline__ u32 pack2(float a, float b) {
    return (u32)f2u(a) | ((u32)f2u(b) << 16);
}
// MODE 0: inputs are bf16. MODE 1: inputs are f32.
template<int MODE> __device__ __forceinline__ float ld(const void* p, long i) {
    if (MODE == 0) return bfu(((const u16*)p)[i]);
    return ((const float*)p)[i];
}
template<int MODE> __device__ __forceinline__ void st_out(void* p, long i, float v) {
    if (MODE == 0) ((u16*)p)[i] = f2u(v);
    else ((float*)p)[i] = v;
}

// ---------------- dtype detector: bf16 data has no wild exponents; f32 read as u16 does.
__global__ void detect_kernel(const u16* w, int* flag) {
    int hits = 0;
    for (int i = threadIdx.x; i < 2048; i += 64) {
        unsigned e = (w[i] >> 7) & 0xFFu;
        if (e >= 132u || (e > 0u && e <= 90u)) hits++;
    }
    for (int o = 32; o; o >>= 1) hits += __shfl_down(hits, o);
    if (threadIdx.x == 0) flag[0] = (hits > 64) ? 1 : 0;
}

// ---------------- prep: transpose Wd2/Wg1/Wg2/Wq/Wk/Wv/Wf1/Wo into MFMA B-layouts ----
template<int MODE>
__global__ __launch_bounds__(256) void prep_kernel(
    const void* __restrict__ Wd2, const void* __restrict__ Wg1, const void* __restrict__ Wg2,
    const void* __restrict__ Wo, const void* __restrict__ Wq, const void* __restrict__ Wk,
    const void* __restrict__ Wv, const void* __restrict__ Wf1,
    u16* __restrict__ WdT2, u16* __restrict__ WgT1, u16* __restrict__ WgT2,
    u16* __restrict__ WoT, u16* __restrict__ WqT, u16* __restrict__ WkT,
    u16* __restrict__ WvT, u16* __restrict__ WfT, const int* __restrict__ flag) {
    if (flag[0] != MODE) return;
    int idx = blockIdx.x * 256 + threadIdx.x;
    if (idx < 6 * 16384) {
        int m = idx >> 14, o = idx & 16383;
        int n = o >> 7, i = o & 127;
        const void* W = (m == 0) ? Wd2 : (m == 1) ? Wg1 : (m == 2) ? Wg2
                      : (m == 3) ? Wq  : (m == 4) ? Wk  : Wv;
        u16* D = (m == 0) ? WdT2 : (m == 1) ? WgT1 : (m == 2) ? WgT2
               : (m == 3) ? WqT  : (m == 4) ? WkT  : WvT;
        D[o] = f2u(ld<MODE>(W, (long)i * 128 + n));   // W^T[n][i]
    } else {
        int o = idx - 6 * 16384;
        if (o < 8192) {
            int n = o >> 6, k2 = o & 63;
            WfT[o] = f2u(ld<MODE>(Wf1, (long)k2 * 128 + n));   // Wf1^T[n][k]
        } else {
            int o2 = o - 8192;
            if (o2 < 8192) {
                int col = o2 >> 7, i = o2 & 127;
                WoT[o2] = f2u(ld<MODE>(Wo, (long)i * 64 + col));  // Wo^T[col][i]
            }
        }
    }
}

// ---------------- Kernel 1 (MFMA): f = feat@Wf1+bf1 ; q=f@Wq ; kf=f@Wk ; vf=f@Wv ----
template<int MODE>
__global__ __launch_bounds__(256) void qkv_kernel(
    const void* __restrict__ feat, const void* __restrict__ bf1v,
    const u16* __restrict__ WfT, const u16* __restrict__ WqT,
    const u16* __restrict__ WkT, const u16* __restrict__ WvT,
    u16* __restrict__ qw, u16* __restrict__ kfw, u16* __restrict__ vfw,
    const int* __restrict__ flag) {
    if (flag[0] != MODE) return;
    __shared__ __align__(16) u16 sFeat[64 * 72];
    __shared__ __align__(16) u16 sW[DMODEL * SWS];
    __shared__ __align__(16) u16 sF[64 * SWS];
    const int t = threadIdx.x;
    const int p0 = blockIdx.x * 64;
    const int lane = t & 63, w = t >> 6;
    const int rg = (w & 1) * 32, cg = (w >> 1) * 64;
    const int lm = lane & 15, lq = lane >> 4;

    for (int i = t; i < 512; i += 256) {
        int r = i >> 3, c8 = i & 7;
        u16 tmp[8];
        if (MODE == 0) {
            *(uint4*)tmp = *((const uint4*)feat + (long)(p0 + r) * 8 + c8);
        } else {
            const float* fp = (const float*)feat + (long)(p0 + r) * 64 + c8 * 8;
#pragma unroll
            for (int u = 0; u < 8; ++u) tmp[u] = f2u(fp[u]);
        }
        *(uint4*)(sFeat + r * 72 + c8 * 8) = *(uint4*)tmp;
    }
    for (int i = t; i < 1024; i += 256) {
        int r = i >> 3, c8 = i & 7;
        *(uint4*)(sW + r * SWS + c8 * 8) = ((const uint4*)WfT)[i];
    }
    __syncthreads();

    {
        f32x4 acc[2][4];
#pragma unroll
        for (int rt = 0; rt < 2; ++rt)
#pragma unroll
            for (int ct = 0; ct < 4; ++ct) { acc[rt][ct][0]=0.f; acc[rt][ct][1]=0.f; acc[rt][ct][2]=0.f; acc[rt][ct][3]=0.f; }
#pragma unroll
        for (int kk = 0; kk < 2; ++kk) {
            const int ko = kk * 32 + lq * 8;
            bh8 a0 = *(const bh8*)(sFeat + (rg + lm) * 72 + ko);
            bh8 a1 = *(const bh8*)(sFeat + (rg + 16 + lm) * 72 + ko);
            bh8 bq[4];
#pragma unroll
            for (int ct = 0; ct < 4; ++ct)
                bq[ct] = *(const bh8*)(sW + (cg + ct * 16 + lm) * SWS + ko);
#pragma unroll
            for (int ct = 0; ct < 4; ++ct) {
                acc[0][ct] = __builtin_amdgcn_mfma_f32_16x16x32_bf16(a0, bq[ct], acc[0][ct], 0, 0, 0);
                acc[1][ct] = __builtin_amdgcn_mfma_f32_16x16x32_bf16(a1, bq[ct], acc[1][ct], 0, 0, 0);
            }
        }
        __syncthreads();
#pragma unroll
        for (int rt = 0; rt < 2; ++rt)
#pragma unroll
            for (int ct = 0; ct < 4; ++ct) {
                const int col = cg + ct * 16 + lm;
                const float bj = ld<MODE>(bf1v, col);
#pragma unroll
                for (int r4 = 0; r4 < 4; ++r4) {
                    int row = rg + rt * 16 + lq * 4 + r4;
                    sF[row * SWS + col] = f2u(acc[rt][ct][r4] + bj);
                }
            }
    }
    __syncthreads();

    const u16* Ws[3] = {WqT, WkT, WvT};
    u16* Os[3] = {qw, kfw, vfw};
#pragma unroll 1
    for (int m = 0; m < 3; ++m) {
        for (int i = t; i < 2048; i += 256) {
            int r = i >> 4, c8 = i & 15;
            *(uint4*)(sW + r * SWS + c8 * 8) = ((const uint4*)Ws[m])[i];
        }
        __syncthreads();
        f32x4 acc[2][4];
#pragma unroll
        for (int rt = 0; rt < 2; ++rt)
#pragma unroll
            for (int ct = 0; ct < 4; ++ct) { acc[rt][ct][0]=0.f; acc[rt][ct][1]=0.f; acc[rt][ct][2]=0.f; acc[rt][ct][3]=0.f; }
#pragma unroll
        for (int kk = 0; kk < 4; ++kk) {
            const int ko = kk * 32 + lq * 8;
            bh8 a0 = *(const bh8*)(sF + (rg + lm) * SWS + ko);
            bh8 a1 = *(const bh8*)(sF + (rg + 16 + lm) * SWS + ko);
            bh8 bq[4];
#pragma unroll
            for (int ct = 0; ct < 4; ++ct)
                bq[ct] = *(const bh8*)(sW + (cg + ct * 16 + lm) * SWS + ko);
#pragma unroll
            for (int ct = 0; ct < 4; ++ct) {
                acc[0][ct] = __builtin_amdgcn_mfma_f32_16x16x32_bf16(a0, bq[ct], acc[0][ct], 0, 0, 0);
                acc[1][ct] = __builtin_amdgcn_mfma_f32_16x16x32_bf16(a1, bq[ct], acc[1][ct], 0, 0, 0);
            }
        }
#pragma unroll
        for (int rt = 0; rt < 2; ++rt)
#pragma unroll
            for (int ct = 0; ct < 4; ++ct) {
                const int col = cg + ct * 16 + lm;
#pragma unroll
                for (int r4 = 0; r4 < 4; ++r4) {
                    int row = rg + rt * 16 + lq * 4 + r4;
                    Os[m][(long)(p0 + row) * DMODEL + col] = f2u(acc[rt][ct][r4]);
                }
            }
        __syncthreads();
    }
}

// ---------------- Kernel 2: KNN, wave-cooperative top-16. One wave per point. -------
template<int MODE>
__global__ __launch_bounds__(256) void knn_kernel(
    const void* __restrict__ xyz, int* __restrict__ knnIdx, const int* __restrict__ flag) {
    if (flag[0] != MODE) return;
    __shared__ __align__(8) u16 sXyz[NPTS * 4];
    __shared__ float sN2[NPTS];
    const int t = threadIdx.x;
    const int p0 = blockIdx.x * 4;
    const long xb = (long)(p0 >> 12) * NPTS * 3;
    for (int m = t; m < NPTS; m += 256) {
        float gx = ld<MODE>(xyz, xb + m * 3 + 0);
        float gy = ld<MODE>(xyz, xb + m * 3 + 1);
        float gz = ld<MODE>(xyz, xb + m * 3 + 2);
        uint2 pk;
        pk.x = (u32)f2u(gx) | ((u32)f2u(gy) << 16);
        pk.y = (u32)f2u(gz);
        *(uint2*)(sXyz + m * 4) = pk;
        sN2[m] = gx * gx + gy * gy + gz * gz;
    }
    __syncthreads();
    const int w = t >> 6, lane = t & 63;
    const int pl = (p0 & (NPTS - 1)) + w;
    uint2 qv = *(const uint2*)(sXyz + pl * 4);
    const float px = __uint_as_float(qv.x << 16);
    const float py = __uint_as_float(qv.x & 0xFFFF0000u);
    const float pz = __uint_as_float(qv.y << 16);
    float kd = 3e38f; int ki = 0;
    float T = 3e38f;
#pragma unroll 1
    for (int it = 0; it < NPTS / 64; ++it) {
        const int c = it * 64 + lane;
        uint2 cd = *(const uint2*)(sXyz + c * 4);
        float cx = __uint_as_float(cd.x << 16);
        float cy = __uint_as_float(cd.x & 0xFFFF0000u);
        float cz = __uint_as_float(cd.y << 16);
        float key = sN2[c] - 2.f * (px * cx + py * cy + pz * cz);
        unsigned long long mask = __ballot(key < T);
        while (mask) {
            int l = __ffsll(mask) - 1;
            mask &= mask - 1;
            float kk = __uint_as_float(__builtin_amdgcn_readlane(__float_as_uint(key), l));
            if (kk < T) {
                int ii = it * 64 + l;
                float pkd = __shfl_up(kd, 1);
                int   pki = __shfl_up(ki, 1);
                if (lane == 0) pkd = -3e38f;
                bool pg = pkd > kk, cg = kd > kk;
                kd = pg ? pkd : (cg ? kk : kd);
                ki = pg ? pki : (cg ? ii : ki);
                T = __uint_as_float(__builtin_amdgcn_readlane(__float_as_uint(kd), 15));
            }
        }
    }
    if (lane < 16) knnIdx[(long)(p0 + w) * 16 + lane] = ki;
}

// ---- 8-wave MFMA phase: D[64x128] = sIn @ W (+bias, opt relu) -> sOut (packed b32 epi)
// Wave w: rows (w&1)*32..+32, cols (w>>1)*32..+32 as 2x2 tiles of 16x16. 16 MFMA/wave.
__device__ __forceinline__ void mfma_phase8(const u16* sIn, const u16* sWm,
                                            const float* bias, bool dorelu, bool inplace,
                                            u16* sOut, int t) {
    const int lane = t & 63, w = t >> 6;
    const int rg = (w & 1) * 32, cg = (w >> 1) * 32;
    const int lm = lane & 15, lq = lane >> 4;
    f32x4 acc[2][2];
#pragma unroll
    for (int rt = 0; rt < 2; ++rt)
#pragma unroll
        for (int ct = 0; ct < 2; ++ct) { acc[rt][ct][0]=0.f; acc[rt][ct][1]=0.f; acc[rt][ct][2]=0.f; acc[rt][ct][3]=0.f; }
#pragma unroll
    for (int kk = 0; kk < 4; ++kk) {
        const int ko = kk * 32 + lq * 8;
        bh8 a0 = *(const bh8*)(sIn + (rg + lm) * SWS + ko);
        bh8 a1 = *(const bh8*)(sIn + (rg + 16 + lm) * SWS + ko);
        bh8 b0 = *(const bh8*)(sWm + (cg + lm) * SWS + ko);
        bh8 b1 = *(const bh8*)(sWm + (cg + 16 + lm) * SWS + ko);
        acc[0][0] = __builtin_amdgcn_mfma_f32_16x16x32_bf16(a0, b0, acc[0][0], 0, 0, 0);
        acc[0][1] = __builtin_amdgcn_mfma_f32_16x16x32_bf16(a0, b1, acc[0][1], 0, 0, 0);
        acc[1][0] = __builtin_amdgcn_mfma_f32_16x16x32_bf16(a1, b0, acc[1][0], 0, 0, 0);
        acc[1][1] = __builtin_amdgcn_mfma_f32_16x16x32_bf16(a1, b1, acc[1][1], 0, 0, 0);
    }
    if (inplace) __syncthreads();   // all frag reads complete before overwrite
#pragma unroll
    for (int rt = 0; rt < 2; ++rt)
#pragma unroll
        for (int ct = 0; ct < 2; ++ct) {
            const int col = cg + ct * 16 + lm;
            const float bj = bias[col];
#pragma unroll
            for (int r4 = 0; r4 < 4; ++r4) {
                int row = rg + rt * 16 + lq * 4 + r4;
                float v = acc[rt][ct][r4] + bj;
                if (dorelu) v = fmaxf(v, 0.f);
                u32 u = (u32)f2u(v);
                u32 o = __shfl_xor(u, 1);                 // partner col^1, same row
                if ((lane & 1) == 0)
                    *(u32*)(sOut + row * SWS + col) = u | (o << 16);
            }
        }
}

// ---------------- Kernel 3: persistent-weights fused attention -----------------------
// Grid 256 (1 block/CU), 512 threads (8 waves). Weights LDS-resident; 16 groups x 4 pts.
template<int MODE>
__global__ __launch_bounds__(512, 2) void att_kernel(
    const void* __restrict__ xyz, const void* __restrict__ feat,
    const void* __restrict__ Wd1, const void* __restrict__ bd1, const void* __restrict__ bd2,
    const void* __restrict__ bg1, const void* __restrict__ bg2, const void* __restrict__ bo,
    const u16* __restrict__ WdT2, const u16* __restrict__ WgT1, const u16* __restrict__ WgT2,
    const u16* __restrict__ WoT,
    const u16* __restrict__ qw, const u16* __restrict__ kfw, const u16* __restrict__ vfw,
    const int* __restrict__ knnIdx, const int* __restrict__ flag,
    void* __restrict__ out) {
    if (flag[0] != MODE) return;
    __shared__ __align__(16) u16 sW1[DMODEL * SWS];   // Wd2^T  (34816 B)
    __shared__ __align__(16) u16 sW2[DMODEL * SWS];   // Wg1^T
    __shared__ __align__(16) u16 sW3[DMODEL * SWS];   // Wg2^T
    __shared__ __align__(16) u16 sA[64 * SWS];        // H1 -> A -> G -> logits
    __shared__ __align__(16) u16 sPE[64 * SWS];
    __shared__ __align__(16) u16 sResB[16 * SWS];     // res rows 0..3 (4..15 zero)
    __shared__ __align__(16) float sRel[64][4];
    __shared__ float sBias[3 * DMODEL];               // bd2 | bg1 | bg2
    __shared__ u16  sQ[4 * DMODEL];
    __shared__ int  sIdx[64];

    const int t = threadIdx.x;
    const int lane = t & 63, w = t >> 6;
    const int blk = blockIdx.x;
    const long bbase = (long)((blk * 64) >> 12) * NPTS;

    // ---- once: stage weights, biases, zero sResB, per-thread Wd1 regs
    for (int i = t; i < 2048; i += 512) {
        int r = i >> 4, c8 = i & 15;
        *(uint4*)(sW1 + r * SWS + c8 * 8) = ((const uint4*)WdT2)[i];
        *(uint4*)(sW2 + r * SWS + c8 * 8) = ((const uint4*)WgT1)[i];
        *(uint4*)(sW3 + r * SWS + c8 * 8) = ((const uint4*)WgT2)[i];
    }
    if (t < 128) {
        sBias[t]       = ld<MODE>(bd2, t);
        sBias[128 + t] = ld<MODE>(bg1, t);
        sBias[256 + t] = ld<MODE>(bg2, t);
    }
    for (int i = t; i < 16 * SWS / 2; i += 512) ((u32*)sResB)[i] = 0;
    const int ch = 2 * lane;
    const float wd0a = ld<MODE>(Wd1, ch),       wd0b = ld<MODE>(Wd1, ch + 1);
    const float wd1a = ld<MODE>(Wd1, 128 + ch), wd1b = ld<MODE>(Wd1, 128 + ch + 1);
    const float wd2a = ld<MODE>(Wd1, 256 + ch), wd2b = ld<MODE>(Wd1, 256 + ch + 1);
    const float bd1a = ld<MODE>(bd1, ch),       bd1b = ld<MODE>(bd1, ch + 1);

    // ---- stage group 0 (threads 256..511)
    if (t >= 256) {
        int i = t - 256;
        int pn = blk * 64;
        ((u32*)sQ)[i] = ((const u32*)(qw + (long)pn * DMODEL))[i];
        if (i < 64) {
            int id = knnIdx[(long)pn * KNBR + i];
            sIdx[i] = id;
            long nb = bbase + id;
            int pl = i >> 4;
            sRel[i][0] = ld<MODE>(xyz, ((long)pn + pl) * 3 + 0) - ld<MODE>(xyz, nb * 3 + 0);
            sRel[i][1] = ld<MODE>(xyz, ((long)pn + pl) * 3 + 1) - ld<MODE>(xyz, nb * 3 + 1);
            sRel[i][2] = ld<MODE>(xyz, ((long)pn + pl) * 3 + 2) - ld<MODE>(xyz, nb * 3 + 2);
        }
    }

#pragma unroll 1
    for (int g = 0; g < 16; ++g) {
        const int p0 = blk * 64 + g * 4;
        __syncthreads();                               // (A) stage of g complete

        // H1 = relu(rel@Wd1+bd1) -> sA  (rows w*8..w*8+7, channel pair 2*lane)
#pragma unroll
        for (int i = 0; i < 8; ++i) {
            int r = w * 8 + i;
            float4 rl = *(const float4*)sRel[r];
            float h0 = fmaxf(bd1a + rl.x * wd0a + rl.y * wd1a + rl.z * wd2a, 0.f);
            float h1 = fmaxf(bd1b + rl.x * wd0b + rl.y * wd1b + rl.z * wd2b, 0.f);
            *(u32*)(sA + r * SWS + ch) = pack2(h0, h1);
        }
        __syncthreads();                               // (B)

        mfma_phase8(sA, sW1, sBias, false, false, sPE, t);       // PE
        __syncthreads();                               // (C)

        // A = q - kf + pe -> sA
#pragma unroll
        for (int i = 0; i < 8; ++i) {
            int r = w * 8 + i;
            u32 kv2 = *(const u32*)(kfw + (bbase + sIdx[r]) * (long)DMODEL + ch);
            u32 qv2 = *(const u32*)(sQ + (r >> 4) * DMODEL + ch);
            u32 pe2 = *(const u32*)(sPE + r * SWS + ch);
            float a0 = bfu((u16)qv2) - bfu((u16)kv2) + bfu((u16)pe2);
            float a1 = bfu((u16)(qv2 >> 16)) - bfu((u16)(kv2 >> 16)) + bfu((u16)(pe2 >> 16));
            *(u32*)(sA + r * SWS + ch) = pack2(a0, a1);
        }
        __syncthreads();                               // (D)

        mfma_phase8(sA, sW2, sBias + 128, true, true, sA, t);    // G = relu(A@Wg1+bg1)
        __syncthreads();                               // (E)
        mfma_phase8(sA, sW3, sBias + 256, false, true, sA, t);   // logits
        __syncthreads();                               // (F)

        // softmax over k (waves 0..3; wave = point, lane = channel pair)
        if (w < 4) {
            const int pl = w;
            float lg0[16], lg1[16];
            float mx0 = -3e38f, mx1 = -3e38f;
#pragma unroll
            for (int k = 0; k < KNBR; ++k) {
                u32 l2 = *(const u32*)(sA + (pl * 16 + k) * SWS + ch);
                lg0[k] = bfu((u16)l2); lg1[k] = bfu((u16)(l2 >> 16));
                mx0 = fmaxf(mx0, lg0[k]); mx1 = fmaxf(mx1, lg1[k]);
            }
            const float inv = 0.08838834764831845f;    // 1/sqrt(128)
            float s0 = 0.f, s1 = 0.f, r0 = 0.f, r1 = 0.f;
#pragma unroll
            for (int k = 0; k < KNBR; ++k) {
                u32 v2 = *(const u32*)(vfw + (bbase + sIdx[pl * 16 + k]) * (long)DMODEL + ch);
                u32 p2 = *(const u32*)(sPE + (pl * 16 + k) * SWS + ch);
                float e0 = __expf((lg0[k] - mx0) * inv);
                float e1 = __expf((lg1[k] - mx1) * inv);
                s0 += e0; s1 += e1;
                r0 += e0 * (bfu((u16)v2) + bfu((u16)p2));
                r1 += e1 * (bfu((u16)(v2 >> 16)) + bfu((u16)(p2 >> 16)));
            }
            *(u32*)(sResB + pl * SWS + ch) = pack2(r0 / s0, r1 / s1);
        }
        __syncthreads();                               // (G)

        // final out (waves 0..3): C[4x64] = res @ Wo + bo + shortcut, via MFMA
        if (w < 4) {
            const int lm = lane & 15, lq = lane >> 4;
            const int col = w * 16 + lm;
            f32x4 acc = {0.f, 0.f, 0.f, 0.f};
#pragma unroll
            for (int kk = 0; kk < 4; ++kk) {
                const int ko = kk * 32 + lq * 8;
                bh8 a = *(const bh8*)(sResB + lm * SWS + ko);
                bh8 b = *(const bh8*)(WoT + (long)col * DMODEL + ko);
                acc = __builtin_amdgcn_mfma_f32_16x16x32_bf16(a, b, acc, 0, 0, 0);
            }
            if (lq == 0) {
                float bov = ld<MODE>(bo, col);
#pragma unroll
                for (int r4 = 0; r4 < 4; ++r4) {
                    long p = p0 + r4;
                    float v = acc[r4] + bov + ld<MODE>(feat, p * DPTS + col);
                    st_out<MODE>(out, p * DPTS + col, v);
                }
            }
        } else if (g + 1 < 16) {                       // waves 4..7: stage group g+1
            int i = t - 256;
            int pn = blk * 64 + (g + 1) * 4;
            ((u32*)sQ)[i] = ((const u32*)(qw + (long)pn * DMODEL))[i];
            if (i < 64) {
                int id = knnIdx[(long)pn * KNBR + i];
                sIdx[i] = id;
                long nb = bbase + id;
                int pl = i >> 4;
                sRel[i][0] = ld<MODE>(xyz, ((long)pn + pl) * 3 + 0) - ld<MODE>(xyz, nb * 3 + 0);
                sRel[i][1] = ld<MODE>(xyz, ((long)pn + pl) * 3 + 1) - ld<MODE>(xyz, nb * 3 + 1);
                sRel[i][2] = ld<MODE>(xyz, ((long)pn + pl) * 3 + 2) - ld<MODE>(xyz, nb * 3 + 2);
            }
        }
    }
}

extern "C" void kernel_launch(void* const* d_in, const int* in_sizes, int n_in,
                              void* d_out, int out_size, void* d_ws, size_t ws_size,
                              hipStream_t stream) {
    (void)in_sizes; (void)n_in; (void)out_size; (void)ws_size;
    char* ws = (char*)d_ws;
    int* flag = (int*)ws;
    int* idx  = (int*)(ws + 256);
    u16* qw   = (u16*)(ws + 256 + (long)BN * KNBR * 4);
    u16* kfw  = qw + (long)BN * DMODEL;
    u16* vfw  = kfw + (long)BN * DMODEL;
    u16* WdT2 = vfw + (long)BN * DMODEL;
    u16* WgT1 = WdT2 + 16384;
    u16* WgT2 = WgT1 + 16384;
    u16* WoT  = WgT2 + 16384;
    u16* WqT  = WoT + 8192;
    u16* WkT  = WqT + 16384;
    u16* WvT  = WkT + 16384;
    u16* WfT  = WvT + 16384;                  // total ws ~13.6 MB

    detect_kernel<<<1, 64, 0, stream>>>((const u16*)d_in[8], flag);

    prep_kernel<0><<<448, 256, 0, stream>>>(d_in[4], d_in[11], d_in[13], d_in[15],
                                            d_in[8], d_in[9], d_in[10], d_in[6],
                                            WdT2, WgT1, WgT2, WoT, WqT, WkT, WvT, WfT, flag);
    prep_kernel<1><<<448, 256, 0, stream>>>(d_in[4], d_in[11], d_in[13], d_in[15],
                                            d_in[8], d_in[9], d_in[10], d_in[6],
                                            WdT2, WgT1, WgT2, WoT, WqT, WkT, WvT, WfT, flag);
    qkv_kernel<0><<<BN / 64, 256, 0, stream>>>(d_in[1], d_in[7], WfT, WqT, WkT, WvT,
                                               qw, kfw, vfw, flag);
    qkv_kernel<1><<<BN / 64, 256, 0, stream>>>(d_in[1], d_in[7], WfT, WqT, WkT, WvT,
                                               qw, kfw, vfw, flag);
    knn_kernel<0><<<BN / 4, 256, 0, stream>>>(d_in[0], idx, flag);
    knn_kernel<1><<<BN / 4, 256, 0, stream>>>(d_in[0], idx, flag);
    att_kernel<0><<<BN / 64, 512, 0, stream>>>(d_in[0], d_in[1], d_in[2], d_in[3], d_in[5],
                                               d_in[12], d_in[14], d_in[16],
                                               WdT2, WgT1, WgT2, WoT,
                                               qw, kfw, vfw, idx, flag, d_out);
    att_kernel<1><<<BN / 64, 512, 0, stream>>>(d_in[0], d_in[1], d_in[2], d_in[3], d_in[5],
                                               d_in[12], d_in[14], d_in[16],
                                               WdT2, WgT1, WgT2, WoT,
                                               qw, kfw, vfw, idx, flag, d_out);
}